// Round 12
// baseline (669.838 us; speedup 1.0000x reference)
//
#include <hip/hip_runtime.h>
#include <hip/hip_bf16.h>

#define N_FP 10000
#define EMB 64
#define L_CONV 5
#define CC 256
#define HID 512
#define N_NODES 40000
#define N_EDGES 640000
#define N_GRAPHS 128
#define MP 40064           // N_NODES padded to multiple of 128
#define SCAN_BLOCKS 157    // ceil(40000/256)
#define POOL_CHUNK 128
#define POOL_BLOCKS 313    // ceil(40000/128)
#define WSCALE 0.25f       // per-conv-layer weight scale (relu-homogeneous)
#define UNSCALE 4096.0f    // 4^6, exact power of two
#define ROWBLKS 313        // MP/128
// Activations stored SLICE-MAJOR: x[ch>>5][node][ch&31], slice stride MP*32 shorts (64B rows).
// Aggregation blocks with blockIdx%8==s touch only slice s -> XCD-affine -> L2-resident
// (mechanism verified in r10: FETCH 134->24 MB).

typedef __attribute__((ext_vector_type(8))) _Float16 half8;
typedef __attribute__((ext_vector_type(4))) float f32x4;

// ---------- f16 helpers ----------
__device__ inline float h2f(unsigned int bits16) {
  return (float)__builtin_bit_cast(_Float16, (unsigned short)bits16);
}
__device__ inline unsigned short f2h(float x) {
  return __builtin_bit_cast(unsigned short, (_Float16)x);
}

// ---------------- CSR build ----------------
__global__ void zero_ints(int* __restrict__ p, int n) {
  int i = blockIdx.x * blockDim.x + threadIdx.x;
  if (i < n) p[i] = 0;
}

__global__ void count_deg(const int* __restrict__ dst, int* __restrict__ deg) {
  int e = blockIdx.x * blockDim.x + threadIdx.x;
  if (e < N_EDGES) atomicAdd(&deg[dst[e]], 1);
}

__global__ void scan_partial(const int* __restrict__ deg, int* __restrict__ partial) {
  __shared__ int sm[256];
  int t = threadIdx.x;
  int idx = blockIdx.x * 256 + t;
  sm[t] = (idx < N_NODES) ? deg[idx] : 0;
  __syncthreads();
  for (int off = 128; off > 0; off >>= 1) {
    if (t < off) sm[t] += sm[t + off];
    __syncthreads();
  }
  if (t == 0) partial[blockIdx.x] = sm[0];
}

__global__ void scan_top(int* __restrict__ partial) {
  __shared__ int sm[256];
  int t = threadIdx.x;
  int own = (t < SCAN_BLOCKS) ? partial[t] : 0;
  sm[t] = own;
  __syncthreads();
  for (int off = 1; off < 256; off <<= 1) {
    int v = (t >= off) ? sm[t - off] : 0;
    __syncthreads();
    sm[t] += v;
    __syncthreads();
  }
  if (t < SCAN_BLOCKS) partial[t] = sm[t] - own;  // exclusive
}

__global__ void scan_final(const int* __restrict__ deg, const int* __restrict__ partial,
                           int* __restrict__ offs, int* __restrict__ cursor) {
  __shared__ int sm[256];
  int t = threadIdx.x;
  int idx = blockIdx.x * 256 + t;
  int own = (idx < N_NODES) ? deg[idx] : 0;
  sm[t] = own;
  __syncthreads();
  for (int off = 1; off < 256; off <<= 1) {
    int v = (t >= off) ? sm[t - off] : 0;
    __syncthreads();
    sm[t] += v;
    __syncthreads();
  }
  int excl = sm[t] - own + partial[blockIdx.x];
  if (idx < N_NODES) { offs[idx] = excl; cursor[idx] = excl; }
  if (idx == N_NODES - 1) offs[N_NODES] = excl + own;
}

__global__ void scatter_edges(const int* __restrict__ src, const int* __restrict__ dst,
                              int* __restrict__ cursor, int* __restrict__ csr) {
  int e = blockIdx.x * blockDim.x + threadIdx.x;
  if (e < N_EDGES) {
    int d = dst[e];
    int slot = atomicAdd(&cursor[d], 1);
    csr[slot] = src[e];
  }
}

// ---------------- weight transpose + scale -> f16 [N][K] ----------------
__global__ void transpose_scale_f16(const float* __restrict__ W, unsigned short* __restrict__ out,
                                    int K, int N, float scale) {
  int i = blockIdx.x * 256 + threadIdx.x;
  if (i >= K * N) return;
  int k = i / N, n = i % N;
  out[(size_t)n * K + k] = f2h(W[i] * scale);
}

__global__ void transpose_scale_all_f16(const float* __restrict__ W, unsigned short* __restrict__ out,
                                        float scale) {
  int i = blockIdx.x * 256 + threadIdx.x;
  if (i >= L_CONV * CC * CC) return;
  int l = i >> 16;
  int rem = i & 65535;
  int k = rem >> 8, n = rem & 255;
  out[((size_t)l << 16) + n * CC + k] = f2h(W[i] * scale);
}

// ---------------- embedding gather -> f16 sliced ----------------
__global__ void embed_gather_f16(const int* __restrict__ x_idx, const float* __restrict__ emb,
                                 unsigned short* __restrict__ x0) {
  int i = blockIdx.x * 256 + threadIdx.x;
  int n = i >> 6;
  int c = i & 63;
  x0[(size_t)(c >> 5) * (MP * 32) + (size_t)n * 32 + (c & 31)] =
      f2h(emb[(size_t)x_idx[n] * EMB + c]);
}

// ---------------- aggregation (64 ch): wave/node, sliced addressing ----------------
__global__ void aggregate64_f16(const unsigned short* __restrict__ xp, const int* __restrict__ offs,
                                const int* __restrict__ csr, unsigned short* __restrict__ aggp) {
  int wid = (blockIdx.x * blockDim.x + threadIdx.x) >> 6;
  int lane = threadIdx.x & 63;
  if (wid >= N_NODES) return;
  int gr = lane >> 3;     // edge slot 0..7
  int sl = lane & 7;      // 8 lanes x 8 halves = 64 ch
  const unsigned short* __restrict__ xb =
      xp + (size_t)(sl >> 2) * (MP * 32) + (sl & 3) * 8;
  int s = offs[wid], e = offs[wid + 1];
  float a0 = 0.f, a1 = 0.f, a2 = 0.f, a3 = 0.f, a4 = 0.f, a5 = 0.f, a6 = 0.f, a7 = 0.f;
  int j = s + gr;
  for (; j + 8 < e; j += 16) {
    int sv0 = csr[j];
    int sv1 = csr[j + 8];
    uint4 v0 = *(const uint4*)(xb + (size_t)sv0 * 32);
    uint4 v1 = *(const uint4*)(xb + (size_t)sv1 * 32);
    a0 += h2f(v0.x & 0xffff); a1 += h2f(v0.x >> 16);
    a2 += h2f(v0.y & 0xffff); a3 += h2f(v0.y >> 16);
    a4 += h2f(v0.z & 0xffff); a5 += h2f(v0.z >> 16);
    a6 += h2f(v0.w & 0xffff); a7 += h2f(v0.w >> 16);
    a0 += h2f(v1.x & 0xffff); a1 += h2f(v1.x >> 16);
    a2 += h2f(v1.y & 0xffff); a3 += h2f(v1.y >> 16);
    a4 += h2f(v1.z & 0xffff); a5 += h2f(v1.z >> 16);
    a6 += h2f(v1.w & 0xffff); a7 += h2f(v1.w >> 16);
  }
  if (j < e) {
    int sv = csr[j];
    uint4 v = *(const uint4*)(xb + (size_t)sv * 32);
    a0 += h2f(v.x & 0xffff); a1 += h2f(v.x >> 16);
    a2 += h2f(v.y & 0xffff); a3 += h2f(v.y >> 16);
    a4 += h2f(v.z & 0xffff); a5 += h2f(v.z >> 16);
    a6 += h2f(v.w & 0xffff); a7 += h2f(v.w >> 16);
  }
#pragma unroll
  for (int off = 32; off >= 8; off >>= 1) {
    a0 += __shfl_down(a0, off); a1 += __shfl_down(a1, off);
    a2 += __shfl_down(a2, off); a3 += __shfl_down(a3, off);
    a4 += __shfl_down(a4, off); a5 += __shfl_down(a5, off);
    a6 += __shfl_down(a6, off); a7 += __shfl_down(a7, off);
  }
  if (lane < 8) {
    uint4 o;
    o.x = (unsigned int)f2h(a0) | ((unsigned int)f2h(a1) << 16);
    o.y = (unsigned int)f2h(a2) | ((unsigned int)f2h(a3) << 16);
    o.z = (unsigned int)f2h(a4) | ((unsigned int)f2h(a5) << 16);
    o.w = (unsigned int)f2h(a6) | ((unsigned int)f2h(a7) << 16);
    *(uint4*)(aggp + (size_t)(lane >> 2) * (MP * 32) + (size_t)wid * 32 + (lane & 3) * 8) = o;
  }
}

// ---------------- sliced aggregation v2: lane-per-(node x quad), no shuffles ----------------
// slice = bid%8 (XCD-affine); 64 nodes/block; each lane serially accumulates its node's
// edges for one 16B quad; 16 independent nodes/wave x2 unroll = 32 loads in flight.
__global__ __launch_bounds__(256)
void aggregate_lane8(const unsigned short* __restrict__ xs, const int* __restrict__ offs,
                     const int* __restrict__ csr, unsigned short* __restrict__ aggs) {
  const int slice = blockIdx.x & 7;
  const int chunk = blockIdx.x >> 3;
  const unsigned short* __restrict__ xp = xs + (size_t)slice * (MP * 32);
  unsigned short* __restrict__ ap = aggs + (size_t)slice * (MP * 32);
  const int wave = threadIdx.x >> 6;
  const int lane = threadIdx.x & 63;
  const int ns = lane >> 2;      // node slot 0..15
  const int quad = lane & 3;     // 16B quad within 64B slice row
  const int n = chunk * 64 + wave * 16 + ns;   // 625*64 = 40000 exactly
  const unsigned short* __restrict__ xq = xp + quad * 8;
  int s = offs[n], e = offs[n + 1];
  float a0 = 0.f, a1 = 0.f, a2 = 0.f, a3 = 0.f, a4 = 0.f, a5 = 0.f, a6 = 0.f, a7 = 0.f;
  int j = s;
  for (; j + 1 < e; j += 2) {
    int sv0 = __builtin_nontemporal_load(csr + j);
    int sv1 = __builtin_nontemporal_load(csr + j + 1);
    uint4 v0 = *(const uint4*)(xq + (size_t)sv0 * 32);
    uint4 v1 = *(const uint4*)(xq + (size_t)sv1 * 32);
    a0 += h2f(v0.x & 0xffff); a1 += h2f(v0.x >> 16);
    a2 += h2f(v0.y & 0xffff); a3 += h2f(v0.y >> 16);
    a4 += h2f(v0.z & 0xffff); a5 += h2f(v0.z >> 16);
    a6 += h2f(v0.w & 0xffff); a7 += h2f(v0.w >> 16);
    a0 += h2f(v1.x & 0xffff); a1 += h2f(v1.x >> 16);
    a2 += h2f(v1.y & 0xffff); a3 += h2f(v1.y >> 16);
    a4 += h2f(v1.z & 0xffff); a5 += h2f(v1.z >> 16);
    a6 += h2f(v1.w & 0xffff); a7 += h2f(v1.w >> 16);
  }
  if (j < e) {
    int sv = __builtin_nontemporal_load(csr + j);
    uint4 v = *(const uint4*)(xq + (size_t)sv * 32);
    a0 += h2f(v.x & 0xffff); a1 += h2f(v.x >> 16);
    a2 += h2f(v.y & 0xffff); a3 += h2f(v.y >> 16);
    a4 += h2f(v.z & 0xffff); a5 += h2f(v.z >> 16);
    a6 += h2f(v.w & 0xffff); a7 += h2f(v.w >> 16);
  }
  uint4 o;
  o.x = (unsigned int)f2h(a0) | ((unsigned int)f2h(a1) << 16);
  o.y = (unsigned int)f2h(a2) | ((unsigned int)f2h(a3) << 16);
  o.z = (unsigned int)f2h(a4) | ((unsigned int)f2h(a5) << 16);
  o.w = (unsigned int)f2h(a6) | ((unsigned int)f2h(a7) << 16);
  *(uint4*)(ap + (size_t)n * 32 + quad * 8) = o;
}

// ---------------- MFMA f16 dual GEMM: gload_lds + XOR swizzle + XCD-pair map, SLICED A ----------------
template<int K1>
__global__ __launch_bounds__(256)
void gemm_conv_f16(const unsigned short* __restrict__ A1, const unsigned short* __restrict__ A2,
                   const unsigned short* __restrict__ W1, const unsigned short* __restrict__ W2,
                   const float* __restrict__ bias, float bscale,
                   unsigned short* __restrict__ outp) {
  __shared__ __align__(16) unsigned short smem[2 * 128 * 64];
  unsigned short* As = smem;
  unsigned short* Bs = smem + 128 * 64;

  const int bid = blockIdx.x;
  const int rb = (bid >> 4) * 8 + (bid & 7);
  if (rb >= ROWBLKS) return;
  const int row0 = rb * 128;
  const int col0 = ((bid >> 3) & 1) * 128;

  const int t = threadIdx.x;
  const int lane = t & 63;
  const int wave = t >> 6;
  const int wm = wave >> 1;
  const int wn = wave & 1;
  const int fr = lane & 15;
  const int fg = lane >> 4;

  f32x4 acc[4][4];
#pragma unroll
  for (int i = 0; i < 4; ++i)
#pragma unroll
    for (int j = 0; j < 4; ++j) acc[i][j] = (f32x4)(0.f);

  for (int srcp = 0; srcp < 2; ++srcp) {
    const unsigned short* __restrict__ A = srcp ? A2 : A1;
    const unsigned short* __restrict__ W = srcp ? W2 : W1;
    for (int ks = 0; ks < K1 / 64; ++ks) {
      const int kb = ks * 64;
#pragma unroll
      for (int i = 0; i < 4; ++i) {
        int P = i * 256 + t;            // LDS 16B-chunk position
        int r = P >> 3;                 // tile row
        int q = (P & 7) ^ (r & 7);      // logical k-chunk fetched into this slot
        int ch = kb + q * 8;            // channel of this chunk
        const unsigned short* ga =
            A + (size_t)(ch >> 5) * (MP * 32) + (size_t)(row0 + r) * 32 + (ch & 31);
        const unsigned short* gw = W + (size_t)(col0 + r) * K1 + kb + q * 8;
        __builtin_amdgcn_global_load_lds(
            (const __attribute__((address_space(1))) unsigned int*)ga,
            (__attribute__((address_space(3))) unsigned int*)(As + P * 8), 16, 0, 0);
        __builtin_amdgcn_global_load_lds(
            (const __attribute__((address_space(1))) unsigned int*)gw,
            (__attribute__((address_space(3))) unsigned int*)(Bs + P * 8), 16, 0, 0);
      }
      __syncthreads();

#pragma unroll
      for (int sub = 0; sub < 2; ++sub) {
        const int q = sub * 4 + fg;     // logical k-chunk for this fragment
        half8 ah[4];
#pragma unroll
        for (int mi = 0; mi < 4; ++mi) {
          int ar = wm * 64 + mi * 16 + fr;
          ah[mi] = *(const half8*)(As + (ar * 8 + (q ^ (ar & 7))) * 8);
        }
#pragma unroll
        for (int ni = 0; ni < 4; ++ni) {
          int rn = wn * 64 + ni * 16 + fr;
          half8 bh = *(const half8*)(Bs + (rn * 8 + (q ^ (rn & 7))) * 8);
#pragma unroll
          for (int mi = 0; mi < 4; ++mi) {
            acc[mi][ni] = __builtin_amdgcn_mfma_f32_16x16x32_f16(ah[mi], bh, acc[mi][ni], 0, 0, 0);
          }
        }
      }
      __syncthreads();
    }
  }

  // epilogue: bias + relu -> LDS C-tile (f16), then coalesced uint4 stores to SLICED layout
#pragma unroll
  for (int ni = 0; ni < 4; ++ni) {
    int col = wn * 64 + ni * 16 + fr;
    float b = bias[col0 + col] * bscale;
#pragma unroll
    for (int mi = 0; mi < 4; ++mi) {
#pragma unroll
      for (int r = 0; r < 4; ++r) {
        int row = wm * 64 + mi * 16 + fg * 4 + r;
        float v = fmaxf(acc[mi][ni][r] + b, 0.f);
        smem[row * 128 + col] = f2h(v);
      }
    }
  }
  __syncthreads();
#pragma unroll
  for (int p = 0; p < 8; ++p) {
    int idx = p * 2048 + t * 8;       // shorts
    int row = idx >> 7;
    int c = col0 + (idx & 127);
    *(uint4*)(outp + (size_t)(c >> 5) * (MP * 32) + (size_t)(row0 + row) * 32 + (c & 31)) =
        *(const uint4*)(smem + idx);
  }
}

// ---------------- global_add_pool: chunked, atomic flush, unscale (sliced input) ----------------
__global__ void pool_chunk_f16(const unsigned short* __restrict__ xp, const int* __restrict__ batch,
                               float* __restrict__ gb) {
  int wave = threadIdx.x >> 6;
  int lane = threadIdx.x & 63;
  const unsigned short* base = xp + (size_t)(lane >> 3) * (MP * 32) + (lane & 7) * 4;
  int c0 = blockIdx.x * POOL_CHUNK;
  int c1 = min(c0 + POOL_CHUNK, N_NODES);
  float a0 = 0.f, a1 = 0.f, a2 = 0.f, a3 = 0.f;
  int curb = -1;
  for (int i = c0 + wave; i < c1; i += 4) {
    int b = batch[i];
    if (b != curb) {
      if (curb >= 0) {
        float* g = gb + (size_t)curb * 256 + lane * 4;
        atomicAdd(g + 0, a0 * UNSCALE); atomicAdd(g + 1, a1 * UNSCALE);
        atomicAdd(g + 2, a2 * UNSCALE); atomicAdd(g + 3, a3 * UNSCALE);
      }
      curb = b;
      a0 = a1 = a2 = a3 = 0.f;
    }
    uint2 v = *(const uint2*)(base + (size_t)i * 32);
    a0 += h2f(v.x & 0xffff); a1 += h2f(v.x >> 16);
    a2 += h2f(v.y & 0xffff); a3 += h2f(v.y >> 16);
  }
  if (curb >= 0) {
    float* g = gb + (size_t)curb * 256 + lane * 4;
    atomicAdd(g + 0, a0 * UNSCALE); atomicAdd(g + 1, a1 * UNSCALE);
    atomicAdd(g + 2, a2 * UNSCALE); atomicAdd(g + 3, a3 * UNSCALE);
  }
}

// ---------------- MLP linear: 4 graphs x 128 outputs per block, fp32 ----------------
template<int K, int N, bool RELU>
__global__ __launch_bounds__(512)
void mlp_linear(const float* __restrict__ A, const float* __restrict__ W,
                const float* __restrict__ bias, float* __restrict__ out) {
  __shared__ float a[4][K];
  const int t = threadIdx.x;
  const int g0 = blockIdx.x * 4;
  const int n0 = blockIdx.y * 128;
#pragma unroll
  for (int i = 0; i < (4 * K) / 512; ++i) {
    int idx = t + i * 512;
    a[idx / K][idx % K] = A[(size_t)g0 * K + idx];
  }
  __syncthreads();
  const int gl = t >> 7;          // graph slot 0..3
  const int n = n0 + (t & 127);
  const float* __restrict__ ar = a[gl];
  const float* __restrict__ w = W + n;
  float acc = bias[n];
#pragma unroll 8
  for (int k = 0; k < K; ++k) acc = fmaf(ar[k], w[(size_t)k * N], acc);
  if (RELU) acc = fmaxf(acc, 0.f);
  out[(size_t)(g0 + gl) * N + n] = acc;
}

__global__ void out_layer(const float* __restrict__ h, const float* __restrict__ w,
                          const float* __restrict__ b, float* __restrict__ out) {
  int g = blockIdx.x;
  int t = threadIdx.x; // 64
  float acc = 0.f;
#pragma unroll 4
  for (int k = t; k < HID; k += 64) acc = fmaf(h[(size_t)g * HID + k], w[k], acc);
  for (int off = 32; off > 0; off >>= 1) acc += __shfl_down(acc, off);
  if (t == 0) out[g] = acc + b[0];
}

extern "C" void kernel_launch(void* const* d_in, const int* in_sizes, int n_in,
                              void* d_out, int out_size, void* d_ws, size_t ws_size,
                              hipStream_t stream) {
  const int* x_idx = (const int*)d_in[0];
  const int* edge_index = (const int*)d_in[1];
  const int* batch = (const int*)d_in[2];
  const float* embed = (const float*)d_in[3];
  const float* w_rel0 = (const float*)d_in[4];
  const float* b_rel0 = (const float*)d_in[5];
  const float* w_root0 = (const float*)d_in[6];
  const float* w_rel = (const float*)d_in[7];
  const float* b_rel = (const float*)d_in[8];
  const float* w_root = (const float*)d_in[9];
  const float* w_lin0 = (const float*)d_in[10];
  const float* b_lin0 = (const float*)d_in[11];
  const float* w_lin = (const float*)d_in[12];
  const float* b_lin = (const float*)d_in[13];
  const float* w_out = (const float*)d_in[14];
  const float* b_out = (const float*)d_in[15];
  float* out = (float*)d_out;

  const int* src = edge_index;
  const int* dst = edge_index + N_EDGES;

  char* ws = (char*)d_ws;
  size_t off = 0;
  auto alloc = [&](size_t bytes) -> void* {
    void* p = ws + off;
    off = (off + bytes + 255) & ~(size_t)255;
    return p;
  };
  int* deg     = (int*)alloc((size_t)N_NODES * 4);
  int* cursor  = (int*)alloc((size_t)N_NODES * 4);
  int* offs    = (int*)alloc((size_t)(N_NODES + 1) * 4);
  int* partial = (int*)alloc((size_t)SCAN_BLOCKS * 4);
  int* csr     = (int*)alloc((size_t)N_EDGES * 4);
  unsigned short* x0  = (unsigned short*)alloc((size_t)MP * EMB * 2);
  unsigned short* agg = (unsigned short*)alloc((size_t)MP * CC * 2);
  unsigned short* xA  = (unsigned short*)alloc((size_t)MP * CC * 2);
  unsigned short* xB  = (unsigned short*)alloc((size_t)MP * CC * 2);
  unsigned short* w0rel_t  = (unsigned short*)alloc((size_t)CC * EMB * 2);
  unsigned short* w0root_t = (unsigned short*)alloc((size_t)CC * EMB * 2);
  unsigned short* wrel_t  = (unsigned short*)alloc((size_t)L_CONV * CC * CC * 2);
  unsigned short* wroot_t = (unsigned short*)alloc((size_t)L_CONV * CC * CC * 2);
  float* gb = (float*)alloc((size_t)N_GRAPHS * CC * 4);
  float* h1 = (float*)alloc((size_t)N_GRAPHS * HID * 4);
  float* h2 = (float*)alloc((size_t)N_GRAPHS * HID * 4);

  // CSR build (parallel scan)
  zero_ints<<<(N_NODES + 255) / 256, 256, 0, stream>>>(deg, N_NODES);
  count_deg<<<N_EDGES / 256, 256, 0, stream>>>(dst, deg);
  scan_partial<<<SCAN_BLOCKS, 256, 0, stream>>>(deg, partial);
  scan_top<<<1, 256, 0, stream>>>(partial);
  scan_final<<<SCAN_BLOCKS, 256, 0, stream>>>(deg, partial, offs, cursor);
  scatter_edges<<<N_EDGES / 256, 256, 0, stream>>>(src, dst, cursor, csr);

  // weight prep: transpose + scale -> f16
  transpose_scale_f16<<<(EMB * CC + 255) / 256, 256, 0, stream>>>(w_rel0, w0rel_t, EMB, CC, WSCALE);
  transpose_scale_f16<<<(EMB * CC + 255) / 256, 256, 0, stream>>>(w_root0, w0root_t, EMB, CC, WSCALE);
  transpose_scale_all_f16<<<(L_CONV * CC * CC + 255) / 256, 256, 0, stream>>>(w_rel, wrel_t, WSCALE);
  transpose_scale_all_f16<<<(L_CONV * CC * CC + 255) / 256, 256, 0, stream>>>(w_root, wroot_t, WSCALE);

  // x0 = embed[x_idx] -> f16 sliced (2 slices)
  embed_gather_f16<<<(N_NODES * EMB) / 256, 256, 0, stream>>>(x_idx, embed, x0);

  const int gemm_grid = 640;   // 40 groups x 16 (8 rowblks x 2 colblks), tail blocks exit

  // layer 0: EMB -> CC (bias scale 4^-1)
  aggregate64_f16<<<(N_NODES + 3) / 4, 256, 0, stream>>>(x0, offs, csr, agg);
  gemm_conv_f16<EMB><<<gemm_grid, 256, 0, stream>>>(agg, x0, w0rel_t, w0root_t,
                                                    b_rel0, 0.25f, xA);

  // layers 1..5 (bias scale 4^-(l+2))
  const float bscales[L_CONV] = {0.0625f, 0.015625f, 3.90625e-3f, 9.765625e-4f, 2.44140625e-4f};
  unsigned short *cur = xA, *nxt = xB;
  for (int l = 0; l < L_CONV; ++l) {
    size_t o = (size_t)l * CC * CC;
    aggregate_lane8<<<(N_NODES / 64) * 8, 256, 0, stream>>>(cur, offs, csr, agg);
    gemm_conv_f16<CC><<<gemm_grid, 256, 0, stream>>>(agg, cur, wrel_t + o, wroot_t + o,
                                                     b_rel + (size_t)l * CC, bscales[l], nxt);
    unsigned short* tmp = cur; cur = nxt; nxt = tmp;
  }

  // pooling (unscale 4^6) + MLP
  zero_ints<<<(N_GRAPHS * CC) / 256, 256, 0, stream>>>((int*)gb, N_GRAPHS * CC);
  pool_chunk_f16<<<POOL_BLOCKS, 256, 0, stream>>>(cur, batch, gb);
  mlp_linear<CC, HID, true><<<dim3(N_GRAPHS / 4, HID / 128), 512, 0, stream>>>(gb, w_lin0, b_lin0, h1);
  mlp_linear<HID, HID, true><<<dim3(N_GRAPHS / 4, HID / 128), 512, 0, stream>>>(h1, w_lin, b_lin, h2);
  mlp_linear<HID, HID, true><<<dim3(N_GRAPHS / 4, HID / 128), 512, 0, stream>>>(h2, w_lin + HID * HID, b_lin + HID, h1);
  out_layer<<<N_GRAPHS, 64, 0, stream>>>(h1, w_out, b_out, out);
}

// Round 13
// 558.567 us; speedup vs baseline: 1.1992x; 1.1992x over previous
//
#include <hip/hip_runtime.h>
#include <hip/hip_bf16.h>

#define N_FP 10000
#define EMB 64
#define L_CONV 5
#define CC 256
#define HID 512
#define N_NODES 40000
#define N_EDGES 640000
#define N_GRAPHS 128
#define MP 40064           // N_NODES padded to multiple of 128
#define SCAN_BLOCKS 157    // ceil(40000/256)
#define POOL_CHUNK 128
#define POOL_BLOCKS 313    // ceil(40000/128)
#define WSCALE 0.25f       // per-conv-layer weight scale (relu-homogeneous)
#define UNSCALE 4096.0f    // 4^6, exact power of two
#define ROWBLKS 313        // MP/128

typedef __attribute__((ext_vector_type(8))) _Float16 half8;
typedef __attribute__((ext_vector_type(4))) float f32x4;

// ---------- f16 helpers ----------
__device__ inline float h2f(unsigned int bits16) {
  return (float)__builtin_bit_cast(_Float16, (unsigned short)bits16);
}
__device__ inline unsigned short f2h(float x) {
  return __builtin_bit_cast(unsigned short, (_Float16)x);
}

// ---------------- CSR build ----------------
__global__ void zero_ints(int* __restrict__ p, int n) {
  int i = blockIdx.x * blockDim.x + threadIdx.x;
  if (i < n) p[i] = 0;
}

__global__ void count_deg(const int* __restrict__ dst, int* __restrict__ deg) {
  int e = blockIdx.x * blockDim.x + threadIdx.x;
  if (e < N_EDGES) atomicAdd(&deg[dst[e]], 1);
}

__global__ void scan_partial(const int* __restrict__ deg, int* __restrict__ partial) {
  __shared__ int sm[256];
  int t = threadIdx.x;
  int idx = blockIdx.x * 256 + t;
  sm[t] = (idx < N_NODES) ? deg[idx] : 0;
  __syncthreads();
  for (int off = 128; off > 0; off >>= 1) {
    if (t < off) sm[t] += sm[t + off];
    __syncthreads();
  }
  if (t == 0) partial[blockIdx.x] = sm[0];
}

__global__ void scan_top(int* __restrict__ partial) {
  __shared__ int sm[256];
  int t = threadIdx.x;
  int own = (t < SCAN_BLOCKS) ? partial[t] : 0;
  sm[t] = own;
  __syncthreads();
  for (int off = 1; off < 256; off <<= 1) {
    int v = (t >= off) ? sm[t - off] : 0;
    __syncthreads();
    sm[t] += v;
    __syncthreads();
  }
  if (t < SCAN_BLOCKS) partial[t] = sm[t] - own;  // exclusive
}

__global__ void scan_final(const int* __restrict__ deg, const int* __restrict__ partial,
                           int* __restrict__ offs, int* __restrict__ cursor) {
  __shared__ int sm[256];
  int t = threadIdx.x;
  int idx = blockIdx.x * 256 + t;
  int own = (idx < N_NODES) ? deg[idx] : 0;
  sm[t] = own;
  __syncthreads();
  for (int off = 1; off < 256; off <<= 1) {
    int v = (t >= off) ? sm[t - off] : 0;
    __syncthreads();
    sm[t] += v;
    __syncthreads();
  }
  int excl = sm[t] - own + partial[blockIdx.x];
  if (idx < N_NODES) { offs[idx] = excl; cursor[idx] = excl; }
  if (idx == N_NODES - 1) offs[N_NODES] = excl + own;
}

__global__ void scatter_edges(const int* __restrict__ src, const int* __restrict__ dst,
                              int* __restrict__ cursor, int* __restrict__ csr) {
  int e = blockIdx.x * blockDim.x + threadIdx.x;
  if (e < N_EDGES) {
    int d = dst[e];
    int slot = atomicAdd(&cursor[d], 1);
    csr[slot] = src[e];
  }
}

// ---------------- weight transpose + scale -> f16 [N][K] ----------------
__global__ void transpose_scale_f16(const float* __restrict__ W, unsigned short* __restrict__ out,
                                    int K, int N, float scale) {
  int i = blockIdx.x * 256 + threadIdx.x;
  if (i >= K * N) return;
  int k = i / N, n = i % N;
  out[(size_t)n * K + k] = f2h(W[i] * scale);
}

__global__ void transpose_scale_all_f16(const float* __restrict__ W, unsigned short* __restrict__ out,
                                        float scale) {
  int i = blockIdx.x * 256 + threadIdx.x;
  if (i >= L_CONV * CC * CC) return;
  int l = i >> 16;
  int rem = i & 65535;
  int k = rem >> 8, n = rem & 255;
  out[((size_t)l << 16) + n * CC + k] = f2h(W[i] * scale);
}

// ---------------- embedding gather -> f16 ----------------
__global__ void embed_gather_f16(const int* __restrict__ x_idx, const float* __restrict__ emb,
                                 unsigned short* __restrict__ x0) {
  int i = blockIdx.x * 256 + threadIdx.x;
  int n = i >> 6;
  int c = i & 63;
  x0[i] = f2h(emb[(size_t)x_idx[n] * EMB + c]);
}

// ---------------- aggregation (64 ch): 8 lanes/edge, 16 edges in flight ----------------
__global__ void aggregate64_f16(const unsigned short* __restrict__ xp, const int* __restrict__ offs,
                                const int* __restrict__ csr, unsigned short* __restrict__ aggp) {
  int wid = (blockIdx.x * blockDim.x + threadIdx.x) >> 6;
  int lane = threadIdx.x & 63;
  if (wid >= N_NODES) return;
  int gr = lane >> 3;     // edge slot 0..7
  int sl = lane & 7;      // 8 lanes x 8 halves = 64 ch
  int s = offs[wid], e = offs[wid + 1];
  float a0 = 0.f, a1 = 0.f, a2 = 0.f, a3 = 0.f, a4 = 0.f, a5 = 0.f, a6 = 0.f, a7 = 0.f;
  int j = s + gr;
  for (; j + 8 < e; j += 16) {
    int sv0 = csr[j];
    int sv1 = csr[j + 8];
    uint4 v0 = *(const uint4*)(xp + (size_t)sv0 * 64 + sl * 8);
    uint4 v1 = *(const uint4*)(xp + (size_t)sv1 * 64 + sl * 8);
    a0 += h2f(v0.x & 0xffff); a1 += h2f(v0.x >> 16);
    a2 += h2f(v0.y & 0xffff); a3 += h2f(v0.y >> 16);
    a4 += h2f(v0.z & 0xffff); a5 += h2f(v0.z >> 16);
    a6 += h2f(v0.w & 0xffff); a7 += h2f(v0.w >> 16);
    a0 += h2f(v1.x & 0xffff); a1 += h2f(v1.x >> 16);
    a2 += h2f(v1.y & 0xffff); a3 += h2f(v1.y >> 16);
    a4 += h2f(v1.z & 0xffff); a5 += h2f(v1.z >> 16);
    a6 += h2f(v1.w & 0xffff); a7 += h2f(v1.w >> 16);
  }
  if (j < e) {
    int sv = csr[j];
    uint4 v = *(const uint4*)(xp + (size_t)sv * 64 + sl * 8);
    a0 += h2f(v.x & 0xffff); a1 += h2f(v.x >> 16);
    a2 += h2f(v.y & 0xffff); a3 += h2f(v.y >> 16);
    a4 += h2f(v.z & 0xffff); a5 += h2f(v.z >> 16);
    a6 += h2f(v.w & 0xffff); a7 += h2f(v.w >> 16);
  }
#pragma unroll
  for (int off = 32; off >= 8; off >>= 1) {
    a0 += __shfl_down(a0, off); a1 += __shfl_down(a1, off);
    a2 += __shfl_down(a2, off); a3 += __shfl_down(a3, off);
    a4 += __shfl_down(a4, off); a5 += __shfl_down(a5, off);
    a6 += __shfl_down(a6, off); a7 += __shfl_down(a7, off);
  }
  if (lane < 8) {
    uint4 o;
    o.x = (unsigned int)f2h(a0) | ((unsigned int)f2h(a1) << 16);
    o.y = (unsigned int)f2h(a2) | ((unsigned int)f2h(a3) << 16);
    o.z = (unsigned int)f2h(a4) | ((unsigned int)f2h(a5) << 16);
    o.w = (unsigned int)f2h(a6) | ((unsigned int)f2h(a7) << 16);
    *(uint4*)(aggp + (size_t)wid * 64 + lane * 8) = o;
  }
}

// ---------------- aggregation (256 ch): 16 lanes/edge, 2x unroll = 16 loads in flight ----------------
__global__ void aggregate256_f16(const unsigned short* __restrict__ xp, const int* __restrict__ offs,
                                 const int* __restrict__ csr, unsigned short* __restrict__ aggp) {
  int wid = (blockIdx.x * blockDim.x + threadIdx.x) >> 6;
  int lane = threadIdx.x & 63;
  if (wid >= N_NODES) return;
  int es = lane >> 4;     // edge slot 0..3
  int sl = lane & 15;     // 16 lanes x 2 x 8 halves = 256 ch
  int s = offs[wid], e = offs[wid + 1];
  float a[16];
#pragma unroll
  for (int i = 0; i < 16; ++i) a[i] = 0.f;
  int j = s + es;
  for (; j + 4 < e; j += 8) {
    int sv0 = csr[j];
    int sv1 = csr[j + 4];
    uint4 v0a = *(const uint4*)(xp + (size_t)sv0 * 256 + sl * 8);
    uint4 v0b = *(const uint4*)(xp + (size_t)sv0 * 256 + 128 + sl * 8);
    uint4 v1a = *(const uint4*)(xp + (size_t)sv1 * 256 + sl * 8);
    uint4 v1b = *(const uint4*)(xp + (size_t)sv1 * 256 + 128 + sl * 8);
    a[0] += h2f(v0a.x & 0xffff); a[1] += h2f(v0a.x >> 16);
    a[2] += h2f(v0a.y & 0xffff); a[3] += h2f(v0a.y >> 16);
    a[4] += h2f(v0a.z & 0xffff); a[5] += h2f(v0a.z >> 16);
    a[6] += h2f(v0a.w & 0xffff); a[7] += h2f(v0a.w >> 16);
    a[8]  += h2f(v0b.x & 0xffff); a[9]  += h2f(v0b.x >> 16);
    a[10] += h2f(v0b.y & 0xffff); a[11] += h2f(v0b.y >> 16);
    a[12] += h2f(v0b.z & 0xffff); a[13] += h2f(v0b.z >> 16);
    a[14] += h2f(v0b.w & 0xffff); a[15] += h2f(v0b.w >> 16);
    a[0] += h2f(v1a.x & 0xffff); a[1] += h2f(v1a.x >> 16);
    a[2] += h2f(v1a.y & 0xffff); a[3] += h2f(v1a.y >> 16);
    a[4] += h2f(v1a.z & 0xffff); a[5] += h2f(v1a.z >> 16);
    a[6] += h2f(v1a.w & 0xffff); a[7] += h2f(v1a.w >> 16);
    a[8]  += h2f(v1b.x & 0xffff); a[9]  += h2f(v1b.x >> 16);
    a[10] += h2f(v1b.y & 0xffff); a[11] += h2f(v1b.y >> 16);
    a[12] += h2f(v1b.z & 0xffff); a[13] += h2f(v1b.z >> 16);
    a[14] += h2f(v1b.w & 0xffff); a[15] += h2f(v1b.w >> 16);
  }
  if (j < e) {
    int sv = csr[j];
    uint4 va = *(const uint4*)(xp + (size_t)sv * 256 + sl * 8);
    uint4 vb = *(const uint4*)(xp + (size_t)sv * 256 + 128 + sl * 8);
    a[0] += h2f(va.x & 0xffff); a[1] += h2f(va.x >> 16);
    a[2] += h2f(va.y & 0xffff); a[3] += h2f(va.y >> 16);
    a[4] += h2f(va.z & 0xffff); a[5] += h2f(va.z >> 16);
    a[6] += h2f(va.w & 0xffff); a[7] += h2f(va.w >> 16);
    a[8]  += h2f(vb.x & 0xffff); a[9]  += h2f(vb.x >> 16);
    a[10] += h2f(vb.y & 0xffff); a[11] += h2f(vb.y >> 16);
    a[12] += h2f(vb.z & 0xffff); a[13] += h2f(vb.z >> 16);
    a[14] += h2f(vb.w & 0xffff); a[15] += h2f(vb.w >> 16);
  }
#pragma unroll
  for (int off = 32; off >= 16; off >>= 1) {
#pragma unroll
    for (int i = 0; i < 16; ++i) a[i] += __shfl_down(a[i], off);
  }
  if (lane < 16) {
    uint4 o0, o1;
    o0.x = (unsigned int)f2h(a[0]) | ((unsigned int)f2h(a[1]) << 16);
    o0.y = (unsigned int)f2h(a[2]) | ((unsigned int)f2h(a[3]) << 16);
    o0.z = (unsigned int)f2h(a[4]) | ((unsigned int)f2h(a[5]) << 16);
    o0.w = (unsigned int)f2h(a[6]) | ((unsigned int)f2h(a[7]) << 16);
    o1.x = (unsigned int)f2h(a[8])  | ((unsigned int)f2h(a[9])  << 16);
    o1.y = (unsigned int)f2h(a[10]) | ((unsigned int)f2h(a[11]) << 16);
    o1.z = (unsigned int)f2h(a[12]) | ((unsigned int)f2h(a[13]) << 16);
    o1.w = (unsigned int)f2h(a[14]) | ((unsigned int)f2h(a[15]) << 16);
    *(uint4*)(aggp + (size_t)wid * 256 + sl * 8) = o0;
    *(uint4*)(aggp + (size_t)wid * 256 + 128 + sl * 8) = o1;
  }
}

// ---------------- MFMA f16 dual GEMM, BN=256 (one col-block): A read exactly once ----------------
// 512 threads = 8 waves (2 row x 4 col), each wave 64x64. gload_lds + XOR swizzle staging.
// LDS: As 128x64 (16KB) + Bs 256x64 (32KB); C-tile reuses full 64KB after compute.
template<int K1>
__global__ __launch_bounds__(512)
void gemm_conv_f16(const unsigned short* __restrict__ A1, const unsigned short* __restrict__ A2,
                   const unsigned short* __restrict__ W1, const unsigned short* __restrict__ W2,
                   const float* __restrict__ bias, float bscale,
                   unsigned short* __restrict__ outp) {
  __shared__ __align__(16) unsigned short smem[32768];   // 64 KB
  unsigned short* As = smem;                 // [128][64]
  unsigned short* Bs = smem + 128 * 64;      // [256][64]

  const int row0 = blockIdx.x * 128;
  const int t = threadIdx.x;
  const int lane = t & 63;
  const int wave = t >> 6;
  const int wm = wave >> 2;      // 0..1 : 64-row half
  const int wn = wave & 3;       // 0..3 : 64-col quarter
  const int fr = lane & 15;
  const int fg = lane >> 4;

  f32x4 acc[4][4];
#pragma unroll
  for (int i = 0; i < 4; ++i)
#pragma unroll
    for (int j = 0; j < 4; ++j) acc[i][j] = (f32x4)(0.f);

  for (int srcp = 0; srcp < 2; ++srcp) {
    const unsigned short* __restrict__ A = srcp ? A2 : A1;
    const unsigned short* __restrict__ W = srcp ? W2 : W1;
    for (int ks = 0; ks < K1 / 64; ++ks) {
      const int kb = ks * 64;
      // A tile: 1024 16B-chunks (2/thread)
#pragma unroll
      for (int i = 0; i < 2; ++i) {
        int P = i * 512 + t;
        int r = P >> 3;
        int q = (P & 7) ^ (r & 7);
        const unsigned short* ga = A + (size_t)(row0 + r) * K1 + kb + q * 8;
        __builtin_amdgcn_global_load_lds(
            (const __attribute__((address_space(1))) unsigned int*)ga,
            (__attribute__((address_space(3))) unsigned int*)(As + P * 8), 16, 0, 0);
      }
      // B tile: 2048 16B-chunks (4/thread), all 256 weight rows
#pragma unroll
      for (int i = 0; i < 4; ++i) {
        int P = i * 512 + t;
        int r = P >> 3;
        int q = (P & 7) ^ (r & 7);
        const unsigned short* gw = W + (size_t)r * K1 + kb + q * 8;
        __builtin_amdgcn_global_load_lds(
            (const __attribute__((address_space(1))) unsigned int*)gw,
            (__attribute__((address_space(3))) unsigned int*)(Bs + P * 8), 16, 0, 0);
      }
      __syncthreads();

#pragma unroll
      for (int sub = 0; sub < 2; ++sub) {
        const int q = sub * 4 + fg;
        half8 ah[4];
#pragma unroll
        for (int mi = 0; mi < 4; ++mi) {
          int ar = wm * 64 + mi * 16 + fr;
          ah[mi] = *(const half8*)(As + (ar * 8 + (q ^ (ar & 7))) * 8);
        }
#pragma unroll
        for (int ni = 0; ni < 4; ++ni) {
          int rn = wn * 64 + ni * 16 + fr;
          half8 bh = *(const half8*)(Bs + (rn * 8 + (q ^ (rn & 7))) * 8);
#pragma unroll
          for (int mi = 0; mi < 4; ++mi) {
            acc[mi][ni] = __builtin_amdgcn_mfma_f32_16x16x32_f16(ah[mi], bh, acc[mi][ni], 0, 0, 0);
          }
        }
      }
      __syncthreads();
    }
  }

  // epilogue: bias + relu -> LDS C-tile [128][256] f16 (64KB, reuses staging), coalesced stores
#pragma unroll
  for (int ni = 0; ni < 4; ++ni) {
    int col = wn * 64 + ni * 16 + fr;
    float b = bias[col] * bscale;
#pragma unroll
    for (int mi = 0; mi < 4; ++mi) {
#pragma unroll
      for (int r = 0; r < 4; ++r) {
        int row = wm * 64 + mi * 16 + fg * 4 + r;
        float v = fmaxf(acc[mi][ni][r] + b, 0.f);
        smem[row * 256 + col] = f2h(v);
      }
    }
  }
  __syncthreads();
#pragma unroll
  for (int p = 0; p < 8; ++p) {
    int idx = p * 512 + t;            // 16B chunk id, 0..4095
    int row = idx >> 5;
    int col = (idx & 31) * 8;
    *(uint4*)(outp + (size_t)(row0 + row) * 256 + col) = *(const uint4*)(smem + idx * 8);
  }
}

// ---------------- global_add_pool: chunked, atomic flush, unscale ----------------
__global__ void pool_chunk_f16(const unsigned short* __restrict__ xp, const int* __restrict__ batch,
                               float* __restrict__ gb) {
  int wave = threadIdx.x >> 6;
  int lane = threadIdx.x & 63;
  int c0 = blockIdx.x * POOL_CHUNK;
  int c1 = min(c0 + POOL_CHUNK, N_NODES);
  float a0 = 0.f, a1 = 0.f, a2 = 0.f, a3 = 0.f;
  int curb = -1;
  for (int i = c0 + wave; i < c1; i += 4) {
    int b = batch[i];
    if (b != curb) {
      if (curb >= 0) {
        float* g = gb + (size_t)curb * 256 + lane * 4;
        atomicAdd(g + 0, a0 * UNSCALE); atomicAdd(g + 1, a1 * UNSCALE);
        atomicAdd(g + 2, a2 * UNSCALE); atomicAdd(g + 3, a3 * UNSCALE);
      }
      curb = b;
      a0 = a1 = a2 = a3 = 0.f;
    }
    uint2 v = *(const uint2*)(xp + (size_t)i * 256 + lane * 4);
    a0 += h2f(v.x & 0xffff); a1 += h2f(v.x >> 16);
    a2 += h2f(v.y & 0xffff); a3 += h2f(v.y >> 16);
  }
  if (curb >= 0) {
    float* g = gb + (size_t)curb * 256 + lane * 4;
    atomicAdd(g + 0, a0 * UNSCALE); atomicAdd(g + 1, a1 * UNSCALE);
    atomicAdd(g + 2, a2 * UNSCALE); atomicAdd(g + 3, a3 * UNSCALE);
  }
}

// ---------------- MLP linear: 4 graphs x 128 outputs per block, fp32 ----------------
template<int K, int N, bool RELU>
__global__ __launch_bounds__(512)
void mlp_linear(const float* __restrict__ A, const float* __restrict__ W,
                const float* __restrict__ bias, float* __restrict__ out) {
  __shared__ float a[4][K];
  const int t = threadIdx.x;
  const int g0 = blockIdx.x * 4;
  const int n0 = blockIdx.y * 128;
#pragma unroll
  for (int i = 0; i < (4 * K) / 512; ++i) {
    int idx = t + i * 512;
    a[idx / K][idx % K] = A[(size_t)g0 * K + idx];
  }
  __syncthreads();
  const int gl = t >> 7;          // graph slot 0..3
  const int n = n0 + (t & 127);
  const float* __restrict__ ar = a[gl];
  const float* __restrict__ w = W + n;
  float acc = bias[n];
#pragma unroll 8
  for (int k = 0; k < K; ++k) acc = fmaf(ar[k], w[(size_t)k * N], acc);
  if (RELU) acc = fmaxf(acc, 0.f);
  out[(size_t)(g0 + gl) * N + n] = acc;
}

__global__ void out_layer(const float* __restrict__ h, const float* __restrict__ w,
                          const float* __restrict__ b, float* __restrict__ out) {
  int g = blockIdx.x;
  int t = threadIdx.x; // 64
  float acc = 0.f;
#pragma unroll 4
  for (int k = t; k < HID; k += 64) acc = fmaf(h[(size_t)g * HID + k], w[k], acc);
  for (int off = 32; off > 0; off >>= 1) acc += __shfl_down(acc, off);
  if (t == 0) out[g] = acc + b[0];
}

extern "C" void kernel_launch(void* const* d_in, const int* in_sizes, int n_in,
                              void* d_out, int out_size, void* d_ws, size_t ws_size,
                              hipStream_t stream) {
  const int* x_idx = (const int*)d_in[0];
  const int* edge_index = (const int*)d_in[1];
  const int* batch = (const int*)d_in[2];
  const float* embed = (const float*)d_in[3];
  const float* w_rel0 = (const float*)d_in[4];
  const float* b_rel0 = (const float*)d_in[5];
  const float* w_root0 = (const float*)d_in[6];
  const float* w_rel = (const float*)d_in[7];
  const float* b_rel = (const float*)d_in[8];
  const float* w_root = (const float*)d_in[9];
  const float* w_lin0 = (const float*)d_in[10];
  const float* b_lin0 = (const float*)d_in[11];
  const float* w_lin = (const float*)d_in[12];
  const float* b_lin = (const float*)d_in[13];
  const float* w_out = (const float*)d_in[14];
  const float* b_out = (const float*)d_in[15];
  float* out = (float*)d_out;

  const int* src = edge_index;
  const int* dst = edge_index + N_EDGES;

  char* ws = (char*)d_ws;
  size_t off = 0;
  auto alloc = [&](size_t bytes) -> void* {
    void* p = ws + off;
    off = (off + bytes + 255) & ~(size_t)255;
    return p;
  };
  int* deg     = (int*)alloc((size_t)N_NODES * 4);
  int* cursor  = (int*)alloc((size_t)N_NODES * 4);
  int* offs    = (int*)alloc((size_t)(N_NODES + 1) * 4);
  int* partial = (int*)alloc((size_t)SCAN_BLOCKS * 4);
  int* csr     = (int*)alloc((size_t)N_EDGES * 4);
  unsigned short* x0  = (unsigned short*)alloc((size_t)MP * EMB * 2);
  unsigned short* agg = (unsigned short*)alloc((size_t)MP * CC * 2);
  unsigned short* xA  = (unsigned short*)alloc((size_t)MP * CC * 2);
  unsigned short* xB  = (unsigned short*)alloc((size_t)MP * CC * 2);
  unsigned short* w0rel_t  = (unsigned short*)alloc((size_t)CC * EMB * 2);
  unsigned short* w0root_t = (unsigned short*)alloc((size_t)CC * EMB * 2);
  unsigned short* wrel_t  = (unsigned short*)alloc((size_t)L_CONV * CC * CC * 2);
  unsigned short* wroot_t = (unsigned short*)alloc((size_t)L_CONV * CC * CC * 2);
  float* gb = (float*)alloc((size_t)N_GRAPHS * CC * 4);
  float* h1 = (float*)alloc((size_t)N_GRAPHS * HID * 4);
  float* h2 = (float*)alloc((size_t)N_GRAPHS * HID * 4);

  // CSR build (parallel scan)
  zero_ints<<<(N_NODES + 255) / 256, 256, 0, stream>>>(deg, N_NODES);
  count_deg<<<N_EDGES / 256, 256, 0, stream>>>(dst, deg);
  scan_partial<<<SCAN_BLOCKS, 256, 0, stream>>>(deg, partial);
  scan_top<<<1, 256, 0, stream>>>(partial);
  scan_final<<<SCAN_BLOCKS, 256, 0, stream>>>(deg, partial, offs, cursor);
  scatter_edges<<<N_EDGES / 256, 256, 0, stream>>>(src, dst, cursor, csr);

  // weight prep: transpose + scale -> f16
  transpose_scale_f16<<<(EMB * CC + 255) / 256, 256, 0, stream>>>(w_rel0, w0rel_t, EMB, CC, WSCALE);
  transpose_scale_f16<<<(EMB * CC + 255) / 256, 256, 0, stream>>>(w_root0, w0root_t, EMB, CC, WSCALE);
  transpose_scale_all_f16<<<(L_CONV * CC * CC + 255) / 256, 256, 0, stream>>>(w_rel, wrel_t, WSCALE);
  transpose_scale_all_f16<<<(L_CONV * CC * CC + 255) / 256, 256, 0, stream>>>(w_root, wroot_t, WSCALE);

  // x0 = embed[x_idx] -> f16
  embed_gather_f16<<<(N_NODES * EMB) / 256, 256, 0, stream>>>(x_idx, embed, x0);

  // layer 0: EMB -> CC (bias scale 4^-1)
  aggregate64_f16<<<(N_NODES + 3) / 4, 256, 0, stream>>>(x0, offs, csr, agg);
  gemm_conv_f16<EMB><<<ROWBLKS, 512, 0, stream>>>(agg, x0, w0rel_t, w0root_t,
                                                  b_rel0, 0.25f, xA);

  // layers 1..5 (bias scale 4^-(l+2))
  const float bscales[L_CONV] = {0.0625f, 0.015625f, 3.90625e-3f, 9.765625e-4f, 2.44140625e-4f};
  unsigned short *cur = xA, *nxt = xB;
  for (int l = 0; l < L_CONV; ++l) {
    size_t o = (size_t)l * CC * CC;
    aggregate256_f16<<<(N_NODES + 3) / 4, 256, 0, stream>>>(cur, offs, csr, agg);
    gemm_conv_f16<CC><<<ROWBLKS, 512, 0, stream>>>(agg, cur, wrel_t + o, wroot_t + o,
                                                   b_rel + (size_t)l * CC, bscales[l], nxt);
    unsigned short* tmp = cur; cur = nxt; nxt = tmp;
  }

  // pooling (unscale 4^6) + MLP
  zero_ints<<<(N_GRAPHS * CC) / 256, 256, 0, stream>>>((int*)gb, N_GRAPHS * CC);
  pool_chunk_f16<<<POOL_BLOCKS, 256, 0, stream>>>(cur, batch, gb);
  mlp_linear<CC, HID, true><<<dim3(N_GRAPHS / 4, HID / 128), 512, 0, stream>>>(gb, w_lin0, b_lin0, h1);
  mlp_linear<HID, HID, true><<<dim3(N_GRAPHS / 4, HID / 128), 512, 0, stream>>>(h1, w_lin, b_lin, h2);
  mlp_linear<HID, HID, true><<<dim3(N_GRAPHS / 4, HID / 128), 512, 0, stream>>>(h2, w_lin + HID * HID, b_lin + HID, h1);
  out_layer<<<N_GRAPHS, 64, 0, stream>>>(h1, w_out, b_out, out);
}

// Round 14
// 514.720 us; speedup vs baseline: 1.3014x; 1.0852x over previous
//
#include <hip/hip_runtime.h>
#include <hip/hip_bf16.h>

#define N_FP 10000
#define EMB 64
#define L_CONV 5
#define CC 256
#define HID 512
#define N_NODES 40000
#define N_EDGES 640000
#define N_GRAPHS 128
#define MP 40064           // N_NODES padded to multiple of 128
#define SCAN_BLOCKS 157    // ceil(40000/256)
#define POOL_CHUNK 128
#define POOL_BLOCKS 313    // ceil(40000/128)
#define WSCALE 0.25f       // per-conv-layer weight scale (relu-homogeneous)
#define UNSCALE 4096.0f    // 4^6, exact power of two
#define ROWBLKS 313        // MP/128

typedef __attribute__((ext_vector_type(8))) _Float16 half8;
typedef __attribute__((ext_vector_type(4))) float f32x4;

// ---------- f16 helpers ----------
__device__ inline float h2f(unsigned int bits16) {
  return (float)__builtin_bit_cast(_Float16, (unsigned short)bits16);
}
__device__ inline unsigned short f2h(float x) {
  return __builtin_bit_cast(unsigned short, (_Float16)x);
}

// ---------------- CSR build ----------------
__global__ void zero2(int* __restrict__ a, int na, int* __restrict__ b, int nb) {
  int i = blockIdx.x * blockDim.x + threadIdx.x;
  if (i < na) a[i] = 0;
  int j = i - na;
  if (j >= 0 && j < nb) b[j] = 0;
}

__global__ void count_deg(const int* __restrict__ dst, int* __restrict__ deg) {
  int e = blockIdx.x * blockDim.x + threadIdx.x;
  if (e < N_EDGES) atomicAdd(&deg[dst[e]], 1);
}

__global__ void scan_partial(const int* __restrict__ deg, int* __restrict__ partial) {
  __shared__ int sm[256];
  int t = threadIdx.x;
  int idx = blockIdx.x * 256 + t;
  sm[t] = (idx < N_NODES) ? deg[idx] : 0;
  __syncthreads();
  for (int off = 128; off > 0; off >>= 1) {
    if (t < off) sm[t] += sm[t + off];
    __syncthreads();
  }
  if (t == 0) partial[blockIdx.x] = sm[0];
}

__global__ void scan_top(int* __restrict__ partial) {
  __shared__ int sm[256];
  int t = threadIdx.x;
  int own = (t < SCAN_BLOCKS) ? partial[t] : 0;
  sm[t] = own;
  __syncthreads();
  for (int off = 1; off < 256; off <<= 1) {
    int v = (t >= off) ? sm[t - off] : 0;
    __syncthreads();
    sm[t] += v;
    __syncthreads();
  }
  if (t < SCAN_BLOCKS) partial[t] = sm[t] - own;  // exclusive
}

__global__ void scan_final(const int* __restrict__ deg, const int* __restrict__ partial,
                           int* __restrict__ offs, int* __restrict__ cursor) {
  __shared__ int sm[256];
  int t = threadIdx.x;
  int idx = blockIdx.x * 256 + t;
  int own = (idx < N_NODES) ? deg[idx] : 0;
  sm[t] = own;
  __syncthreads();
  for (int off = 1; off < 256; off <<= 1) {
    int v = (t >= off) ? sm[t - off] : 0;
    __syncthreads();
    sm[t] += v;
    __syncthreads();
  }
  int excl = sm[t] - own + partial[blockIdx.x];
  if (idx < N_NODES) { offs[idx] = excl; cursor[idx] = excl; }
  if (idx == N_NODES - 1) offs[N_NODES] = excl + own;
}

__global__ void scatter_edges(const int* __restrict__ src, const int* __restrict__ dst,
                              int* __restrict__ cursor, int* __restrict__ csr) {
  int e = blockIdx.x * blockDim.x + threadIdx.x;
  if (e < N_EDGES) {
    int d = dst[e];
    int slot = atomicAdd(&cursor[d], 1);
    csr[slot] = src[e];
  }
}

// ---------------- fused weight transpose + scale -> f16 [N][K] ----------------
// segments: [0,16384) w_rel0; [16384,32768) w_root0; then w_rel stack; then w_root stack.
#define SEG0 (EMB * CC)
#define SEGS (L_CONV * CC * CC)
__global__ void transpose_scale_fused(const float* __restrict__ w_rel0,
                                      const float* __restrict__ w_root0,
                                      const float* __restrict__ w_rel,
                                      const float* __restrict__ w_root,
                                      unsigned short* __restrict__ o_rel0,
                                      unsigned short* __restrict__ o_root0,
                                      unsigned short* __restrict__ o_rel,
                                      unsigned short* __restrict__ o_root) {
  int i = blockIdx.x * 256 + threadIdx.x;
  if (i < 2 * SEG0) {
    const float* W = (i < SEG0) ? w_rel0 : w_root0;
    unsigned short* O = (i < SEG0) ? o_rel0 : o_root0;
    int j = (i < SEG0) ? i : i - SEG0;
    int k = j / CC, n = j % CC;
    O[(size_t)n * EMB + k] = f2h(W[j] * WSCALE);
    return;
  }
  int r = i - 2 * SEG0;
  if (r >= 2 * SEGS) return;
  const float* W = (r < SEGS) ? w_rel : w_root;
  unsigned short* O = (r < SEGS) ? o_rel : o_root;
  int j = (r < SEGS) ? r : r - SEGS;
  int l = j >> 16;
  int rem = j & 65535;
  int k = rem >> 8, n = rem & 255;
  O[((size_t)l << 16) + n * CC + k] = f2h(W[j] * WSCALE);
}

// ---------------- embedding gather -> f16 ----------------
__global__ void embed_gather_f16(const int* __restrict__ x_idx, const float* __restrict__ emb,
                                 unsigned short* __restrict__ x0) {
  int i = blockIdx.x * 256 + threadIdx.x;
  int n = i >> 6;
  int c = i & 63;
  x0[i] = f2h(emb[(size_t)x_idx[n] * EMB + c]);
}

// ---------------- aggregation (64 ch): 8 lanes/edge, 16 edges in flight ----------------
__global__ void aggregate64_f16(const unsigned short* __restrict__ xp, const int* __restrict__ offs,
                                const int* __restrict__ csr, unsigned short* __restrict__ aggp) {
  int wid = (blockIdx.x * blockDim.x + threadIdx.x) >> 6;
  int lane = threadIdx.x & 63;
  if (wid >= N_NODES) return;
  int gr = lane >> 3;     // edge slot 0..7
  int sl = lane & 7;      // 8 lanes x 8 halves = 64 ch
  int s = offs[wid], e = offs[wid + 1];
  float a0 = 0.f, a1 = 0.f, a2 = 0.f, a3 = 0.f, a4 = 0.f, a5 = 0.f, a6 = 0.f, a7 = 0.f;
  int j = s + gr;
  for (; j + 8 < e; j += 16) {
    int sv0 = csr[j];
    int sv1 = csr[j + 8];
    uint4 v0 = *(const uint4*)(xp + (size_t)sv0 * 64 + sl * 8);
    uint4 v1 = *(const uint4*)(xp + (size_t)sv1 * 64 + sl * 8);
    a0 += h2f(v0.x & 0xffff); a1 += h2f(v0.x >> 16);
    a2 += h2f(v0.y & 0xffff); a3 += h2f(v0.y >> 16);
    a4 += h2f(v0.z & 0xffff); a5 += h2f(v0.z >> 16);
    a6 += h2f(v0.w & 0xffff); a7 += h2f(v0.w >> 16);
    a0 += h2f(v1.x & 0xffff); a1 += h2f(v1.x >> 16);
    a2 += h2f(v1.y & 0xffff); a3 += h2f(v1.y >> 16);
    a4 += h2f(v1.z & 0xffff); a5 += h2f(v1.z >> 16);
    a6 += h2f(v1.w & 0xffff); a7 += h2f(v1.w >> 16);
  }
  if (j < e) {
    int sv = csr[j];
    uint4 v = *(const uint4*)(xp + (size_t)sv * 64 + sl * 8);
    a0 += h2f(v.x & 0xffff); a1 += h2f(v.x >> 16);
    a2 += h2f(v.y & 0xffff); a3 += h2f(v.y >> 16);
    a4 += h2f(v.z & 0xffff); a5 += h2f(v.z >> 16);
    a6 += h2f(v.w & 0xffff); a7 += h2f(v.w >> 16);
  }
#pragma unroll
  for (int off = 32; off >= 8; off >>= 1) {
    a0 += __shfl_down(a0, off); a1 += __shfl_down(a1, off);
    a2 += __shfl_down(a2, off); a3 += __shfl_down(a3, off);
    a4 += __shfl_down(a4, off); a5 += __shfl_down(a5, off);
    a6 += __shfl_down(a6, off); a7 += __shfl_down(a7, off);
  }
  if (lane < 8) {
    uint4 o;
    o.x = (unsigned int)f2h(a0) | ((unsigned int)f2h(a1) << 16);
    o.y = (unsigned int)f2h(a2) | ((unsigned int)f2h(a3) << 16);
    o.z = (unsigned int)f2h(a4) | ((unsigned int)f2h(a5) << 16);
    o.w = (unsigned int)f2h(a6) | ((unsigned int)f2h(a7) << 16);
    *(uint4*)(aggp + (size_t)wid * 64 + lane * 8) = o;
  }
}

// ---------------- aggregation (256 ch): 16 lanes/edge, 2x unroll = 16 loads in flight ----------------
__global__ void aggregate256_f16(const unsigned short* __restrict__ xp, const int* __restrict__ offs,
                                 const int* __restrict__ csr, unsigned short* __restrict__ aggp) {
  int wid = (blockIdx.x * blockDim.x + threadIdx.x) >> 6;
  int lane = threadIdx.x & 63;
  if (wid >= N_NODES) return;
  int es = lane >> 4;     // edge slot 0..3
  int sl = lane & 15;     // 16 lanes x 2 x 8 halves = 256 ch
  int s = offs[wid], e = offs[wid + 1];
  float a[16];
#pragma unroll
  for (int i = 0; i < 16; ++i) a[i] = 0.f;
  int j = s + es;
  for (; j + 4 < e; j += 8) {
    int sv0 = csr[j];
    int sv1 = csr[j + 4];
    uint4 v0a = *(const uint4*)(xp + (size_t)sv0 * 256 + sl * 8);
    uint4 v0b = *(const uint4*)(xp + (size_t)sv0 * 256 + 128 + sl * 8);
    uint4 v1a = *(const uint4*)(xp + (size_t)sv1 * 256 + sl * 8);
    uint4 v1b = *(const uint4*)(xp + (size_t)sv1 * 256 + 128 + sl * 8);
    a[0] += h2f(v0a.x & 0xffff); a[1] += h2f(v0a.x >> 16);
    a[2] += h2f(v0a.y & 0xffff); a[3] += h2f(v0a.y >> 16);
    a[4] += h2f(v0a.z & 0xffff); a[5] += h2f(v0a.z >> 16);
    a[6] += h2f(v0a.w & 0xffff); a[7] += h2f(v0a.w >> 16);
    a[8]  += h2f(v0b.x & 0xffff); a[9]  += h2f(v0b.x >> 16);
    a[10] += h2f(v0b.y & 0xffff); a[11] += h2f(v0b.y >> 16);
    a[12] += h2f(v0b.z & 0xffff); a[13] += h2f(v0b.z >> 16);
    a[14] += h2f(v0b.w & 0xffff); a[15] += h2f(v0b.w >> 16);
    a[0] += h2f(v1a.x & 0xffff); a[1] += h2f(v1a.x >> 16);
    a[2] += h2f(v1a.y & 0xffff); a[3] += h2f(v1a.y >> 16);
    a[4] += h2f(v1a.z & 0xffff); a[5] += h2f(v1a.z >> 16);
    a[6] += h2f(v1a.w & 0xffff); a[7] += h2f(v1a.w >> 16);
    a[8]  += h2f(v1b.x & 0xffff); a[9]  += h2f(v1b.x >> 16);
    a[10] += h2f(v1b.y & 0xffff); a[11] += h2f(v1b.y >> 16);
    a[12] += h2f(v1b.z & 0xffff); a[13] += h2f(v1b.z >> 16);
    a[14] += h2f(v1b.w & 0xffff); a[15] += h2f(v1b.w >> 16);
  }
  if (j < e) {
    int sv = csr[j];
    uint4 va = *(const uint4*)(xp + (size_t)sv * 256 + sl * 8);
    uint4 vb = *(const uint4*)(xp + (size_t)sv * 256 + 128 + sl * 8);
    a[0] += h2f(va.x & 0xffff); a[1] += h2f(va.x >> 16);
    a[2] += h2f(va.y & 0xffff); a[3] += h2f(va.y >> 16);
    a[4] += h2f(va.z & 0xffff); a[5] += h2f(va.z >> 16);
    a[6] += h2f(va.w & 0xffff); a[7] += h2f(va.w >> 16);
    a[8]  += h2f(vb.x & 0xffff); a[9]  += h2f(vb.x >> 16);
    a[10] += h2f(vb.y & 0xffff); a[11] += h2f(vb.y >> 16);
    a[12] += h2f(vb.z & 0xffff); a[13] += h2f(vb.z >> 16);
    a[14] += h2f(vb.w & 0xffff); a[15] += h2f(vb.w >> 16);
  }
#pragma unroll
  for (int off = 32; off >= 16; off >>= 1) {
#pragma unroll
    for (int i = 0; i < 16; ++i) a[i] += __shfl_down(a[i], off);
  }
  if (lane < 16) {
    uint4 o0, o1;
    o0.x = (unsigned int)f2h(a[0]) | ((unsigned int)f2h(a[1]) << 16);
    o0.y = (unsigned int)f2h(a[2]) | ((unsigned int)f2h(a[3]) << 16);
    o0.z = (unsigned int)f2h(a[4]) | ((unsigned int)f2h(a[5]) << 16);
    o0.w = (unsigned int)f2h(a[6]) | ((unsigned int)f2h(a[7]) << 16);
    o1.x = (unsigned int)f2h(a[8])  | ((unsigned int)f2h(a[9])  << 16);
    o1.y = (unsigned int)f2h(a[10]) | ((unsigned int)f2h(a[11]) << 16);
    o1.z = (unsigned int)f2h(a[12]) | ((unsigned int)f2h(a[13]) << 16);
    o1.w = (unsigned int)f2h(a[14]) | ((unsigned int)f2h(a[15]) << 16);
    *(uint4*)(aggp + (size_t)wid * 256 + sl * 8) = o0;
    *(uint4*)(aggp + (size_t)wid * 256 + 128 + sl * 8) = o1;
  }
}

// ---------------- MFMA f16 dual GEMM: gload_lds + XOR swizzle + XCD-pair bid map ----------------
// Grid = 640 (40 groups x 16). bid -> (rowblk, colblk) such that the two colblks of a
// rowblk are 8 bids apart => same XCD under round-robin => 2nd A-panel read hits L2.
template<int K1>
__global__ __launch_bounds__(256)
void gemm_conv_f16(const unsigned short* __restrict__ A1, const unsigned short* __restrict__ A2,
                   const unsigned short* __restrict__ W1, const unsigned short* __restrict__ W2,
                   const float* __restrict__ bias, float bscale,
                   unsigned short* __restrict__ outp) {
  __shared__ __align__(16) unsigned short smem[2 * 128 * 64];
  unsigned short* As = smem;
  unsigned short* Bs = smem + 128 * 64;

  const int bid = blockIdx.x;
  const int rb = (bid >> 4) * 8 + (bid & 7);
  if (rb >= ROWBLKS) return;
  const int row0 = rb * 128;
  const int col0 = ((bid >> 3) & 1) * 128;

  const int t = threadIdx.x;
  const int lane = t & 63;
  const int wave = t >> 6;
  const int wm = wave >> 1;
  const int wn = wave & 1;
  const int fr = lane & 15;
  const int fg = lane >> 4;

  f32x4 acc[4][4];
#pragma unroll
  for (int i = 0; i < 4; ++i)
#pragma unroll
    for (int j = 0; j < 4; ++j) acc[i][j] = (f32x4)(0.f);

  for (int srcp = 0; srcp < 2; ++srcp) {
    const unsigned short* __restrict__ A = srcp ? A2 : A1;
    const unsigned short* __restrict__ W = srcp ? W2 : W1;
    for (int ks = 0; ks < K1 / 64; ++ks) {
      const int kb = ks * 64;
#pragma unroll
      for (int i = 0; i < 4; ++i) {
        int P = i * 256 + t;            // LDS 16B-chunk position
        int r = P >> 3;                 // tile row
        int q = (P & 7) ^ (r & 7);      // logical k-chunk fetched into this slot
        const unsigned short* ga = A + (size_t)(row0 + r) * K1 + kb + q * 8;
        const unsigned short* gw = W + (size_t)(col0 + r) * K1 + kb + q * 8;
        __builtin_amdgcn_global_load_lds(
            (const __attribute__((address_space(1))) unsigned int*)ga,
            (__attribute__((address_space(3))) unsigned int*)(As + P * 8), 16, 0, 0);
        __builtin_amdgcn_global_load_lds(
            (const __attribute__((address_space(1))) unsigned int*)gw,
            (__attribute__((address_space(3))) unsigned int*)(Bs + P * 8), 16, 0, 0);
      }
      __syncthreads();

#pragma unroll
      for (int sub = 0; sub < 2; ++sub) {
        const int q = sub * 4 + fg;     // logical k-chunk for this fragment
        half8 ah[4];
#pragma unroll
        for (int mi = 0; mi < 4; ++mi) {
          int ar = wm * 64 + mi * 16 + fr;
          ah[mi] = *(const half8*)(As + (ar * 8 + (q ^ (ar & 7))) * 8);
        }
#pragma unroll
        for (int ni = 0; ni < 4; ++ni) {
          int rn = wn * 64 + ni * 16 + fr;
          half8 bh = *(const half8*)(Bs + (rn * 8 + (q ^ (rn & 7))) * 8);
#pragma unroll
          for (int mi = 0; mi < 4; ++mi) {
            acc[mi][ni] = __builtin_amdgcn_mfma_f32_16x16x32_f16(ah[mi], bh, acc[mi][ni], 0, 0, 0);
          }
        }
      }
      __syncthreads();
    }
  }

  // epilogue: bias + relu -> LDS C-tile (f16), then coalesced uint4 stores
#pragma unroll
  for (int ni = 0; ni < 4; ++ni) {
    int col = wn * 64 + ni * 16 + fr;
    float b = bias[col0 + col] * bscale;
#pragma unroll
    for (int mi = 0; mi < 4; ++mi) {
#pragma unroll
      for (int r = 0; r < 4; ++r) {
        int row = wm * 64 + mi * 16 + fg * 4 + r;
        float v = fmaxf(acc[mi][ni][r] + b, 0.f);
        smem[row * 128 + col] = f2h(v);
      }
    }
  }
  __syncthreads();
#pragma unroll
  for (int p = 0; p < 8; ++p) {
    int idx = p * 2048 + t * 8;       // shorts
    int row = idx >> 7;
    int col = idx & 127;
    *(uint4*)(outp + (size_t)(row0 + row) * 256 + col0 + col) = *(const uint4*)(smem + idx);
  }
}

// ---------------- global_add_pool: chunked, atomic flush, unscale ----------------
__global__ void pool_chunk_f16(const unsigned short* __restrict__ xp, const int* __restrict__ batch,
                               float* __restrict__ gb) {
  int wave = threadIdx.x >> 6;
  int lane = threadIdx.x & 63;
  int c0 = blockIdx.x * POOL_CHUNK;
  int c1 = min(c0 + POOL_CHUNK, N_NODES);
  float a0 = 0.f, a1 = 0.f, a2 = 0.f, a3 = 0.f;
  int curb = -1;
  for (int i = c0 + wave; i < c1; i += 4) {
    int b = batch[i];
    if (b != curb) {
      if (curb >= 0) {
        float* g = gb + (size_t)curb * 256 + lane * 4;
        atomicAdd(g + 0, a0 * UNSCALE); atomicAdd(g + 1, a1 * UNSCALE);
        atomicAdd(g + 2, a2 * UNSCALE); atomicAdd(g + 3, a3 * UNSCALE);
      }
      curb = b;
      a0 = a1 = a2 = a3 = 0.f;
    }
    uint2 v = *(const uint2*)(xp + (size_t)i * 256 + lane * 4);
    a0 += h2f(v.x & 0xffff); a1 += h2f(v.x >> 16);
    a2 += h2f(v.y & 0xffff); a3 += h2f(v.y >> 16);
  }
  if (curb >= 0) {
    float* g = gb + (size_t)curb * 256 + lane * 4;
    atomicAdd(g + 0, a0 * UNSCALE); atomicAdd(g + 1, a1 * UNSCALE);
    atomicAdd(g + 2, a2 * UNSCALE); atomicAdd(g + 3, a3 * UNSCALE);
  }
}

// ---------------- MLP linear: 4 graphs x 128 outputs per block, fp32 ----------------
template<int K, int N, bool RELU>
__global__ __launch_bounds__(512)
void mlp_linear(const float* __restrict__ A, const float* __restrict__ W,
                const float* __restrict__ bias, float* __restrict__ out) {
  __shared__ float a[4][K];
  const int t = threadIdx.x;
  const int g0 = blockIdx.x * 4;
  const int n0 = blockIdx.y * 128;
#pragma unroll
  for (int i = 0; i < (4 * K) / 512; ++i) {
    int idx = t + i * 512;
    a[idx / K][idx % K] = A[(size_t)g0 * K + idx];
  }
  __syncthreads();
  const int gl = t >> 7;          // graph slot 0..3
  const int n = n0 + (t & 127);
  const float* __restrict__ ar = a[gl];
  const float* __restrict__ w = W + n;
  float acc = bias[n];
#pragma unroll 8
  for (int k = 0; k < K; ++k) acc = fmaf(ar[k], w[(size_t)k * N], acc);
  if (RELU) acc = fmaxf(acc, 0.f);
  out[(size_t)(g0 + gl) * N + n] = acc;
}

__global__ void out_layer(const float* __restrict__ h, const float* __restrict__ w,
                          const float* __restrict__ b, float* __restrict__ out) {
  int g = blockIdx.x;
  int t = threadIdx.x; // 64
  float acc = 0.f;
#pragma unroll 4
  for (int k = t; k < HID; k += 64) acc = fmaf(h[(size_t)g * HID + k], w[k], acc);
  for (int off = 32; off > 0; off >>= 1) acc += __shfl_down(acc, off);
  if (t == 0) out[g] = acc + b[0];
}

extern "C" void kernel_launch(void* const* d_in, const int* in_sizes, int n_in,
                              void* d_out, int out_size, void* d_ws, size_t ws_size,
                              hipStream_t stream) {
  const int* x_idx = (const int*)d_in[0];
  const int* edge_index = (const int*)d_in[1];
  const int* batch = (const int*)d_in[2];
  const float* embed = (const float*)d_in[3];
  const float* w_rel0 = (const float*)d_in[4];
  const float* b_rel0 = (const float*)d_in[5];
  const float* w_root0 = (const float*)d_in[6];
  const float* w_rel = (const float*)d_in[7];
  const float* b_rel = (const float*)d_in[8];
  const float* w_root = (const float*)d_in[9];
  const float* w_lin0 = (const float*)d_in[10];
  const float* b_lin0 = (const float*)d_in[11];
  const float* w_lin = (const float*)d_in[12];
  const float* b_lin = (const float*)d_in[13];
  const float* w_out = (const float*)d_in[14];
  const float* b_out = (const float*)d_in[15];
  float* out = (float*)d_out;

  const int* src = edge_index;
  const int* dst = edge_index + N_EDGES;

  char* ws = (char*)d_ws;
  size_t off = 0;
  auto alloc = [&](size_t bytes) -> void* {
    void* p = ws + off;
    off = (off + bytes + 255) & ~(size_t)255;
    return p;
  };
  int* deg     = (int*)alloc((size_t)N_NODES * 4);
  int* cursor  = (int*)alloc((size_t)N_NODES * 4);
  int* offs    = (int*)alloc((size_t)(N_NODES + 1) * 4);
  int* partial = (int*)alloc((size_t)SCAN_BLOCKS * 4);
  int* csr     = (int*)alloc((size_t)N_EDGES * 4);
  unsigned short* x0  = (unsigned short*)alloc((size_t)MP * EMB * 2);
  unsigned short* agg = (unsigned short*)alloc((size_t)MP * CC * 2);
  unsigned short* xA  = (unsigned short*)alloc((size_t)MP * CC * 2);
  unsigned short* xB  = (unsigned short*)alloc((size_t)MP * CC * 2);
  unsigned short* w0rel_t  = (unsigned short*)alloc((size_t)CC * EMB * 2);
  unsigned short* w0root_t = (unsigned short*)alloc((size_t)CC * EMB * 2);
  unsigned short* wrel_t  = (unsigned short*)alloc((size_t)L_CONV * CC * CC * 2);
  unsigned short* wroot_t = (unsigned short*)alloc((size_t)L_CONV * CC * CC * 2);
  float* gb = (float*)alloc((size_t)N_GRAPHS * CC * 4);
  float* h1 = (float*)alloc((size_t)N_GRAPHS * HID * 4);
  float* h2 = (float*)alloc((size_t)N_GRAPHS * HID * 4);

  // zero deg + gb in one launch
  zero2<<<(N_NODES + N_GRAPHS * CC + 255) / 256, 256, 0, stream>>>(deg, N_NODES,
                                                                   (int*)gb, N_GRAPHS * CC);
  // CSR build (parallel scan)
  count_deg<<<N_EDGES / 256, 256, 0, stream>>>(dst, deg);
  scan_partial<<<SCAN_BLOCKS, 256, 0, stream>>>(deg, partial);
  scan_top<<<1, 256, 0, stream>>>(partial);
  scan_final<<<SCAN_BLOCKS, 256, 0, stream>>>(deg, partial, offs, cursor);
  scatter_edges<<<N_EDGES / 256, 256, 0, stream>>>(src, dst, cursor, csr);

  // weight prep: fused transpose + scale -> f16
  transpose_scale_fused<<<(2 * SEG0 + 2 * SEGS + 255) / 256, 256, 0, stream>>>(
      w_rel0, w_root0, w_rel, w_root, w0rel_t, w0root_t, wrel_t, wroot_t);

  // x0 = embed[x_idx] -> f16
  embed_gather_f16<<<(N_NODES * EMB) / 256, 256, 0, stream>>>(x_idx, embed, x0);

  const int gemm_grid = 640;   // 40 groups x 16 (8 rowblks x 2 colblks), tail blocks exit

  // layer 0: EMB -> CC (bias scale 4^-1)
  aggregate64_f16<<<(N_NODES + 3) / 4, 256, 0, stream>>>(x0, offs, csr, agg);
  gemm_conv_f16<EMB><<<gemm_grid, 256, 0, stream>>>(agg, x0, w0rel_t, w0root_t,
                                                    b_rel0, 0.25f, xA);

  // layers 1..5 (bias scale 4^-(l+2))
  const float bscales[L_CONV] = {0.0625f, 0.015625f, 3.90625e-3f, 9.765625e-4f, 2.44140625e-4f};
  unsigned short *cur = xA, *nxt = xB;
  for (int l = 0; l < L_CONV; ++l) {
    size_t o = (size_t)l * CC * CC;
    aggregate256_f16<<<(N_NODES + 3) / 4, 256, 0, stream>>>(cur, offs, csr, agg);
    gemm_conv_f16<CC><<<gemm_grid, 256, 0, stream>>>(agg, cur, wrel_t + o, wroot_t + o,
                                                     b_rel + (size_t)l * CC, bscales[l], nxt);
    unsigned short* tmp = cur; cur = nxt; nxt = tmp;
  }

  // pooling (unscale 4^6) + MLP
  pool_chunk_f16<<<POOL_BLOCKS, 256, 0, stream>>>(cur, batch, gb);
  mlp_linear<CC, HID, true><<<dim3(N_GRAPHS / 4, HID / 128), 512, 0, stream>>>(gb, w_lin0, b_lin0, h1);
  mlp_linear<HID, HID, true><<<dim3(N_GRAPHS / 4, HID / 128), 512, 0, stream>>>(h1, w_lin, b_lin, h2);
  mlp_linear<HID, HID, true><<<dim3(N_GRAPHS / 4, HID / 128), 512, 0, stream>>>(h2, w_lin + HID * HID, b_lin + HID, h1);
  out_layer<<<N_GRAPHS, 64, 0, stream>>>(h1, w_out, b_out, out);
}